// Round 3
// baseline (223.902 us; speedup 1.0000x reference)
//
#include <hip/hip_runtime.h>
#include <hip/hip_bf16.h>
#include <math.h>

typedef __attribute__((ext_vector_type(8))) short short8;
typedef __attribute__((ext_vector_type(4))) float f32x4;
typedef __attribute__((ext_vector_type(16))) float f32x16;
typedef __attribute__((ext_vector_type(2))) unsigned uint2v;
typedef __attribute__((ext_vector_type(4))) unsigned uint4v;

#define B_  4
#define T_  2048
#define DM  1024
#define NH  16
#define DH  64
#define BH  (B_*NH)   // 64
#define M_  (B_*T_)   // 8192

static __device__ __forceinline__ short f2bf(float f) {
  unsigned u = __float_as_uint(f);
  unsigned r = (u + 0x7fff + ((u >> 16) & 1)) >> 16;
  return (short)r;
}

static __device__ __forceinline__ unsigned cvtpk(float lo, float hi) {
  unsigned r;
  asm("v_cvt_pk_bf16_f32 %0, %1, %2" : "=v"(r) : "v"(lo), "v"(hi));
  return r;
}

static __device__ __forceinline__ void gload_lds16(const void* g, void* l) {
  __builtin_amdgcn_global_load_lds((const __attribute__((address_space(1))) void*)g,
                                   (__attribute__((address_space(3))) void*)l, 16, 0, 0);
}

// ---------------- fp32 -> bf16 convert (vectorized) ----------------
__global__ void k_cvt(const float4* __restrict__ in, ushort4* __restrict__ out, int n4) {
  int i = blockIdx.x * 256 + threadIdx.x;
  if (i >= n4) return;
  float4 v = in[i];
  ushort4 o;
  o.x = (ushort)f2bf(v.x); o.y = (ushort)f2bf(v.y);
  o.z = (ushort)f2bf(v.z); o.w = (ushort)f2bf(v.w);
  out[i] = o;
}

// ---------------- QKV GEMM: C[m][n] = sum_k A[m][k]*W[n][k] ----------------
// Q,K written [bh][t][dh]; V written TRANSPOSED [bh][dh][t] for attention.
// 1-D grid 1536, XCD-chunked swizzle (T1).
__global__ __launch_bounds__(256) void k_gemm_qkv(
    const short* __restrict__ A,    // [M_, DM] bf16
    const short* __restrict__ W,    // [3*DM, DM] bf16
    short* __restrict__ Qb, short* __restrict__ Kb, short* __restrict__ Vtb) {
  const int tid = threadIdx.x;
  const int w = tid >> 6, l = tid & 63;
  const int wr = w >> 1, wc = w & 1;
  const int fq = l >> 4, fr = l & 15;
  const int id = blockIdx.x;
  const int swz = (id & 7) * 192 + (id >> 3);   // 1536 blocks, 192/XCD
  const int m0 = (swz & 63) * 128;
  const int n0 = (swz >> 6) * 128;

  __shared__ short sA[128 * 32];
  __shared__ short sB[128 * 32];
  f32x4 acc[4][4] = {};

  for (int k0 = 0; k0 < DM; k0 += 32) {
#pragma unroll
    for (int c = 0; c < 2; ++c) {
      int r = w * 32 + c * 16;
      gload_lds16(&A[(size_t)(m0 + r + (l >> 2)) * DM + k0 + (l & 3) * 8], &sA[r * 32]);
      gload_lds16(&W[(size_t)(n0 + r + (l >> 2)) * DM + k0 + (l & 3) * 8], &sB[r * 32]);
    }
    __syncthreads();
    short8 aF[4], bF[4];
#pragma unroll
    for (int m = 0; m < 4; ++m)
      aF[m] = *(const short8*)&sA[(wr * 64 + m * 16 + fr) * 32 + fq * 8];
#pragma unroll
    for (int n = 0; n < 4; ++n)
      bF[n] = *(const short8*)&sB[(wc * 64 + n * 16 + fr) * 32 + fq * 8];
#pragma unroll
    for (int m = 0; m < 4; ++m)
#pragma unroll
      for (int n = 0; n < 4; ++n)
        acc[m][n] = __builtin_amdgcn_mfma_f32_16x16x32_bf16(aF[m], bF[n], acc[m][n], 0, 0, 0);
    __syncthreads();
  }

#pragma unroll
  for (int m = 0; m < 4; ++m) {
    int row0 = m0 + wr * 64 + m * 16 + fq * 4;
#pragma unroll
    for (int n = 0; n < 4; ++n) {
      int col = n0 + wc * 64 + n * 16 + fr;
      int part = col >> 10, cc = col & 1023;
      int h = cc >> 6, dh = cc & 63;
#pragma unroll
      for (int j = 0; j < 4; ++j) {
        int r = row0 + j;
        int b = r >> 11, t = r & 2047;
        short v = f2bf(acc[m][n][j]);
        if (part == 0)      Qb[(((size_t)(b * NH + h) * T_ + t)) * DH + dh] = v;
        else if (part == 1) Kb[(((size_t)(b * NH + h) * T_ + t)) * DH + dh] = v;
        else                Vtb[(((size_t)(b * NH + h) * DH + dh)) * T_ + t] = v;
      }
    }
  }
}

// ---------------- proj GEMM: out[m][n] = sum_k O[m][k]*Wp[n][k] (fp32 out) ----------------
__global__ __launch_bounds__(256) void k_gemm_proj(
    const short* __restrict__ A,    // [M_, DM] bf16 (attention out)
    const short* __restrict__ W,    // [DM, DM] bf16
    float* __restrict__ C) {
  const int tid = threadIdx.x;
  const int w = tid >> 6, l = tid & 63;
  const int wr = w >> 1, wc = w & 1;
  const int fq = l >> 4, fr = l & 15;
  const int id = blockIdx.x;
  const int swz = (id & 7) * 64 + (id >> 3);    // 512 blocks, 64/XCD
  const int m0 = (swz & 63) * 128;
  const int n0 = (swz >> 6) * 128;

  __shared__ short sA[128 * 32];
  __shared__ short sB[128 * 32];
  f32x4 acc[4][4] = {};

  for (int k0 = 0; k0 < DM; k0 += 32) {
#pragma unroll
    for (int c = 0; c < 2; ++c) {
      int r = w * 32 + c * 16;
      gload_lds16(&A[(size_t)(m0 + r + (l >> 2)) * DM + k0 + (l & 3) * 8], &sA[r * 32]);
      gload_lds16(&W[(size_t)(n0 + r + (l >> 2)) * DM + k0 + (l & 3) * 8], &sB[r * 32]);
    }
    __syncthreads();
    short8 aF[4], bF[4];
#pragma unroll
    for (int m = 0; m < 4; ++m)
      aF[m] = *(const short8*)&sA[(wr * 64 + m * 16 + fr) * 32 + fq * 8];
#pragma unroll
    for (int n = 0; n < 4; ++n)
      bF[n] = *(const short8*)&sB[(wc * 64 + n * 16 + fr) * 32 + fq * 8];
#pragma unroll
    for (int m = 0; m < 4; ++m)
#pragma unroll
      for (int n = 0; n < 4; ++n)
        acc[m][n] = __builtin_amdgcn_mfma_f32_16x16x32_bf16(aF[m], bF[n], acc[m][n], 0, 0, 0);
    __syncthreads();
  }

#pragma unroll
  for (int m = 0; m < 4; ++m) {
    int row0 = m0 + wr * 64 + m * 16 + fq * 4;
#pragma unroll
    for (int n = 0; n < 4; ++n) {
      int col = n0 + wc * 64 + n * 16 + fr;
#pragma unroll
      for (int j = 0; j < 4; ++j)
        C[(size_t)(row0 + j) * DM + col] = acc[m][n][j];
    }
  }
}

// ---------------- flash attention v3: dbuf pipeline + XCD locality ----------------
// Block = 128 q rows (4 waves x 32). 512 blocks; 8 pair-blocks of one bh per XCD.
// S^T = K·Q^T  (lane&31 = q, regs = k)  -> in-lane softmax (defer-max).
// O^T = V^T·P  (lane&31 = q, regs = d).
__global__ __launch_bounds__(256, 2) void k_attn3(
    const short* __restrict__ Qb,   // [bh][t][dh]
    const short* __restrict__ Kb,   // [bh][t][dh]
    const short* __restrict__ Vtb,  // [bh][dh][t]
    short* __restrict__ Ob) {       // [b][t][h*64+d] bf16
  const int tid = threadIdx.x;
  const int w = tid >> 6, l = tid & 63;
  const int lq = l & 31, hi = l >> 5;
  const int id = blockIdx.x;
  const int bh = (id & 7) + 8 * (id >> 6);   // 8 bh per XCD; pair-blocks co-XCD
  const int pair = (id >> 3) & 7;
  const int b = bh >> 4, h = bh & 15;
  const float K2 = 0.125f * 1.44269504f;  // 1/sqrt(64) * log2(e)

  __shared__ short lds[16384];  // sK dbuf [2][4096] | sVt dbuf [2][4096]; epi reuse
  short* sK = lds;              // buf*4096
  short* sVt = lds + 8192;      // buf*4096

  auto STAGE = [&](int buf, int kt) {
#pragma unroll
    for (int i = 0; i < 2; ++i) {
      int lin = i * 256 + tid;
      int row = lin >> 3, pseg = lin & 7;
      int gseg = pseg ^ (row & 7);
      gload_lds16(&Kb[((size_t)bh * T_ + kt * 64 + row) * DH + gseg * 8],
                  &sK[buf * 4096 + lin * 8]);
    }
#pragma unroll
    for (int i = 0; i < 2; ++i) {
      int lin = i * 256 + tid;
      int row = lin >> 3, pseg = lin & 7;
      int gseg = pseg ^ (row & 7);
      gload_lds16(&Vtb[((size_t)bh * DH + row) * T_ + kt * 64 + gseg * 8],
                  &sVt[buf * 4096 + lin * 8]);
    }
  };

  for (int ph = 0; ph < 2; ++ph) {
    const int qt = ph ? (15 - pair) : pair;
    const int nkt = 2 * qt + 2;
    const int q0 = qt * 128 + w * 32;
    const int qg = q0 + lq;

    short8 qf[4];
#pragma unroll
    for (int c = 0; c < 4; ++c)
      qf[c] = *(const short8*)&Qb[((size_t)bh * T_ + qg) * DH + c * 16 + hi * 8];
    asm volatile("s_waitcnt vmcnt(0)" ::: "memory");

    float m = -3.0e38f, lsum = 0.f;
    f32x16 oacc[2] = {};

    auto COMPUTE = [&](int kt, int buf) {
      const int koff = buf * 4096, voff = buf * 4096;
      // ---- S^T = K · Q^T ----
      float s[32];
      __builtin_amdgcn_s_setprio(1);
#pragma unroll
      for (int st = 0; st < 2; ++st) {
        f32x16 acc = {};
#pragma unroll
        for (int c = 0; c < 4; ++c) {
          short8 kf = *(const short8*)&sK[koff + (st * 32 + lq) * 64 +
                                          (((2 * c + hi) ^ (lq & 7)) * 8)];
          acc = __builtin_amdgcn_mfma_f32_32x32x16_bf16(kf, qf[c], acc, 0, 0, 0);
        }
#pragma unroll
        for (int r = 0; r < 16; ++r) s[st * 16 + r] = acc[r];
      }
      __builtin_amdgcn_s_setprio(0);

      // ---- causal mask ----
      if (kt * 64 + 63 > q0) {
#pragma unroll
        for (int st = 0; st < 2; ++st)
#pragma unroll
          for (int r = 0; r < 16; ++r) {
            int kg = kt * 64 + st * 32 + (r & 3) + 8 * (r >> 2) + 4 * hi;
            if (kg > qg) s[st * 16 + r] = -1e30f;
          }
      }

      // ---- online softmax, defer-max (T13) ----
      float pm = s[0];
#pragma unroll
      for (int r = 1; r < 32; ++r) pm = fmaxf(pm, s[r]);
      pm = fmaxf(pm, __shfl_xor(pm, 32));
      if (__any(pm > m + 8.f)) {
        float nm = fmaxf(m, pm);
        float alpha = exp2f((m - nm) * K2);
        m = nm;
        lsum *= alpha;
#pragma unroll
        for (int dt = 0; dt < 2; ++dt)
#pragma unroll
          for (int r = 0; r < 16; ++r) oacc[dt][r] *= alpha;
      }
      float nmK = m * K2;
      float rs = 0.f;
#pragma unroll
      for (int r = 0; r < 32; ++r) {
        float p = exp2f(fmaf(s[r], K2, -nmK));
        s[r] = p;
        rs += p;
      }
      rs += __shfl_xor(rs, 32);
      lsum += rs;

      // ---- P -> bf16 B-fragments via cvt_pk + permlane32_swap (T12) ----
      short8 pb[4];
#pragma unroll
      for (int st = 0; st < 2; ++st) {
        unsigned x0 = cvtpk(s[st * 16 + 0], s[st * 16 + 1]);
        unsigned x1 = cvtpk(s[st * 16 + 2], s[st * 16 + 3]);
        unsigned y0 = cvtpk(s[st * 16 + 4], s[st * 16 + 5]);
        unsigned y1 = cvtpk(s[st * 16 + 6], s[st * 16 + 7]);
        uint2v r0 = __builtin_amdgcn_permlane32_swap(x0, y0, false, false);
        uint2v r1 = __builtin_amdgcn_permlane32_swap(x1, y1, false, false);
        unsigned x2 = cvtpk(s[st * 16 + 8], s[st * 16 + 9]);
        unsigned x3 = cvtpk(s[st * 16 + 10], s[st * 16 + 11]);
        unsigned y2 = cvtpk(s[st * 16 + 12], s[st * 16 + 13]);
        unsigned y3 = cvtpk(s[st * 16 + 14], s[st * 16 + 15]);
        uint2v r2 = __builtin_amdgcn_permlane32_swap(x2, y2, false, false);
        uint2v r3 = __builtin_amdgcn_permlane32_swap(x3, y3, false, false);
        uint4v ta, tb;
        ta[0] = r0[0]; ta[1] = r1[0]; ta[2] = r0[1]; ta[3] = r1[1];
        tb[0] = r2[0]; tb[1] = r3[0]; tb[2] = r2[1]; tb[3] = r3[1];
        pb[st * 2 + 0] = __builtin_bit_cast(short8, ta);
        pb[st * 2 + 1] = __builtin_bit_cast(short8, tb);
      }

      // ---- O^T += V^T · P ----
      __builtin_amdgcn_s_setprio(1);
#pragma unroll
      for (int dt = 0; dt < 2; ++dt) {
#pragma unroll
        for (int c = 0; c < 4; ++c) {
          short8 vf = *(const short8*)&sVt[voff + (dt * 32 + lq) * 64 +
                                           (((2 * c + hi) ^ (lq & 7)) * 8)];
          oacc[dt] = __builtin_amdgcn_mfma_f32_32x32x16_bf16(vf, pb[c], oacc[dt], 0, 0, 0);
        }
      }
      __builtin_amdgcn_s_setprio(0);
    };

    // ---- pipelined K/V loop: counted vmcnt, raw barriers (T3/T4) ----
    STAGE(0, 0);
    int cur = 0;
    for (int kt = 0; kt < nkt - 1; ++kt) {
      STAGE(cur ^ 1, kt + 1);
      asm volatile("s_waitcnt vmcnt(4)" ::: "memory");
      __builtin_amdgcn_s_barrier();
      __builtin_amdgcn_sched_barrier(0);
      COMPUTE(kt, cur);
      __builtin_amdgcn_s_barrier();
      cur ^= 1;
    }
    asm volatile("s_waitcnt vmcnt(0)" ::: "memory");
    __builtin_amdgcn_s_barrier();
    __builtin_amdgcn_sched_barrier(0);
    COMPUTE(nkt - 1, cur);

    // ---- epilogue: O^T -> LDS transpose -> coalesced bf16 stores ----
    __syncthreads();  // all waves done with staging buffers
    short* sO = lds + w * 2304;  // [32][72] padded
    float inv = 1.0f / lsum;
#pragma unroll
    for (int dt = 0; dt < 2; ++dt)
#pragma unroll
      for (int r = 0; r < 16; r += 2) {
        int dl = dt * 32 + (r & 3) + 8 * (r >> 2) + 4 * hi;
        unsigned pk2 = cvtpk(oacc[dt][r] * inv, oacc[dt][r + 1] * inv);
        *(unsigned*)&sO[lq * 72 + dl] = pk2;
      }
    __syncthreads();
    {
      int qr = l >> 1, hf = l & 1;
      const int tg = qt * 128 + w * 32 + qr;
#pragma unroll
      for (int ss = 0; ss < 4; ++ss) {
        short8 v = *(const short8*)&sO[qr * 72 + hf * 32 + ss * 8];
        *(short8*)&Ob[((size_t)(b * T_) + tg) * DM + h * 64 + hf * 32 + ss * 8] = v;
      }
    }
    __syncthreads();  // epilogue reads done before next phase restages
  }  // ph
}

extern "C" void kernel_launch(void* const* d_in, const int* in_sizes, int n_in,
                              void* d_out, int out_size, void* d_ws, size_t ws_size,
                              hipStream_t stream) {
  const float* x     = (const float*)d_in[0];   // [4,2048,1024]
  const float* Wqkv  = (const float*)d_in[1];   // [3072,1024]
  const float* Wproj = (const float*)d_in[2];   // [1024,1024]
  float* out = (float*)d_out;

  short* ws = (short*)d_ws;
  short* xbf   = ws;                                  // 8192*1024
  short* wqkvb = xbf + (size_t)M_ * DM;               // 3072*1024
  short* wprjb = wqkvb + (size_t)3 * DM * DM;         // 1024*1024
  short* Qb    = wprjb + (size_t)DM * DM;             // 64*2048*64
  short* Kb    = Qb + (size_t)BH * T_ * DH;
  short* Vtb   = Kb + (size_t)BH * T_ * DH;           // transposed [bh][dh][t]
  short* Ob    = Vtb + (size_t)BH * T_ * DH;          // 8192*1024

  k_cvt<<<(M_ * DM / 4) / 256, 256, 0, stream>>>((const float4*)x, (ushort4*)xbf, M_ * DM / 4);
  k_cvt<<<(3 * DM * DM / 4) / 256, 256, 0, stream>>>((const float4*)Wqkv, (ushort4*)wqkvb, 3 * DM * DM / 4);
  k_cvt<<<(DM * DM / 4) / 256, 256, 0, stream>>>((const float4*)Wproj, (ushort4*)wprjb, DM * DM / 4);

  k_gemm_qkv<<<1536, 256, 0, stream>>>(xbf, wqkvb, Qb, Kb, Vtb);
  k_attn3<<<512, 256, 0, stream>>>(Qb, Kb, Vtb, Ob);
  k_gemm_proj<<<512, 256, 0, stream>>>(Ob, wprjb, out);
}

// Round 4
// 183.462 us; speedup vs baseline: 1.2204x; 1.2204x over previous
//
#include <hip/hip_runtime.h>
#include <hip/hip_bf16.h>
#include <math.h>

typedef __attribute__((ext_vector_type(8))) short short8;
typedef __attribute__((ext_vector_type(4))) float f32x4;
typedef __attribute__((ext_vector_type(16))) float f32x16;
typedef __attribute__((ext_vector_type(2))) unsigned uint2v;
typedef __attribute__((ext_vector_type(4))) unsigned uint4v;

#define B_  4
#define T_  2048
#define DM  1024
#define NH  16
#define DH  64
#define BH  (B_*NH)   // 64
#define M_  (B_*T_)   // 8192

static __device__ __forceinline__ short f2bf(float f) {
  unsigned u = __float_as_uint(f);
  unsigned r = (u + 0x7fff + ((u >> 16) & 1)) >> 16;
  return (short)r;
}

static __device__ __forceinline__ unsigned cvtpk(float lo, float hi) {
  unsigned r;
  asm("v_cvt_pk_bf16_f32 %0, %1, %2" : "=v"(r) : "v"(lo), "v"(hi));
  return r;
}

static __device__ __forceinline__ void gload_lds16(const void* g, void* l) {
  __builtin_amdgcn_global_load_lds((const __attribute__((address_space(1))) void*)g,
                                   (__attribute__((address_space(3))) void*)l, 16, 0, 0);
}

// ---------------- fp32 -> bf16 convert, all three tensors in one launch ----------------
__global__ void k_cvt3(const float4* __restrict__ x, const float4* __restrict__ wq,
                       const float4* __restrict__ wp, ushort4* __restrict__ ox,
                       ushort4* __restrict__ oq, ushort4* __restrict__ op) {
  const int n1 = M_ * DM / 4, n2 = 3 * DM * DM / 4, n3 = DM * DM / 4;
  int i = blockIdx.x * 256 + threadIdx.x;
  const float4* src;
  ushort4* dst;
  int j = i;
  if (i < n1) { src = x; dst = ox; }
  else if (i < n1 + n2) { src = wq; dst = oq; j = i - n1; }
  else if (i < n1 + n2 + n3) { src = wp; dst = op; j = i - n1 - n2; }
  else return;
  float4 v = src[j];
  ushort4 o;
  o.x = (ushort)f2bf(v.x); o.y = (ushort)f2bf(v.y);
  o.z = (ushort)f2bf(v.z); o.w = (ushort)f2bf(v.w);
  dst[j] = o;
}

// ---------------- QKV GEMM: C[m][n] = sum_k A[m][k]*W[n][k] ----------------
// 2-D grid (default dispatch already m-chunks mod-8 per XCD -> A L2-resident).
// Q,K written [bh][t][dh]; V written TRANSPOSED [bh][dh][t] for attention.
__global__ __launch_bounds__(256) void k_gemm_qkv(
    const short* __restrict__ A,    // [M_, DM] bf16
    const short* __restrict__ W,    // [3*DM, DM] bf16
    short* __restrict__ Qb, short* __restrict__ Kb, short* __restrict__ Vtb) {
  const int tid = threadIdx.x;
  const int w = tid >> 6, l = tid & 63;
  const int wr = w >> 1, wc = w & 1;
  const int fq = l >> 4, fr = l & 15;
  const int m0 = blockIdx.x * 128;
  const int n0 = blockIdx.y * 128;

  __shared__ short sA[128 * 32];
  __shared__ short sB[128 * 32];
  f32x4 acc[4][4] = {};

  for (int k0 = 0; k0 < DM; k0 += 32) {
#pragma unroll
    for (int c = 0; c < 2; ++c) {
      int r = w * 32 + c * 16;
      gload_lds16(&A[(size_t)(m0 + r + (l >> 2)) * DM + k0 + (l & 3) * 8], &sA[r * 32]);
      gload_lds16(&W[(size_t)(n0 + r + (l >> 2)) * DM + k0 + (l & 3) * 8], &sB[r * 32]);
    }
    __syncthreads();
    short8 aF[4], bF[4];
#pragma unroll
    for (int m = 0; m < 4; ++m)
      aF[m] = *(const short8*)&sA[(wr * 64 + m * 16 + fr) * 32 + fq * 8];
#pragma unroll
    for (int n = 0; n < 4; ++n)
      bF[n] = *(const short8*)&sB[(wc * 64 + n * 16 + fr) * 32 + fq * 8];
#pragma unroll
    for (int m = 0; m < 4; ++m)
#pragma unroll
      for (int n = 0; n < 4; ++n)
        acc[m][n] = __builtin_amdgcn_mfma_f32_16x16x32_bf16(aF[m], bF[n], acc[m][n], 0, 0, 0);
    __syncthreads();
  }

  // epilogue: block-uniform destination (n-tile lies entirely in one of Q/K/V)
  const int part = n0 >> 10;
  if (part < 2) {
    short* dst = part ? Kb : Qb;
#pragma unroll
    for (int m = 0; m < 4; ++m) {
      int row0 = m0 + wr * 64 + m * 16 + fq * 4;
#pragma unroll
      for (int n = 0; n < 4; ++n) {
        int col = n0 + wc * 64 + n * 16 + fr;
        int h = (col & 1023) >> 6, dh = col & 63;
#pragma unroll
        for (int j = 0; j < 4; ++j) {
          int r = row0 + j;
          int b = r >> 11, t = r & 2047;
          dst[(((size_t)(b * NH + h) * T_ + t)) * DH + dh] = f2bf(acc[m][n][j]);
        }
      }
    }
  } else {
#pragma unroll
    for (int m = 0; m < 4; ++m) {
      int row0 = m0 + wr * 64 + m * 16 + fq * 4;
#pragma unroll
      for (int n = 0; n < 4; ++n) {
        int col = n0 + wc * 64 + n * 16 + fr;
        int h = (col & 1023) >> 6, dh = col & 63;
#pragma unroll
        for (int j = 0; j < 4; ++j) {
          int r = row0 + j;
          int b = r >> 11, t = r & 2047;
          Vtb[(((size_t)(b * NH + h) * DH + dh)) * T_ + t] = f2bf(acc[m][n][j]);
        }
      }
    }
  }
}

// ---------------- proj GEMM: out[m][n] = sum_k O[m][k]*Wp[n][k] (fp32 out) ----------------
__global__ __launch_bounds__(256) void k_gemm_proj(
    const short* __restrict__ A,    // [M_, DM] bf16 (attention out)
    const short* __restrict__ W,    // [DM, DM] bf16
    float* __restrict__ C) {
  const int tid = threadIdx.x;
  const int w = tid >> 6, l = tid & 63;
  const int wr = w >> 1, wc = w & 1;
  const int fq = l >> 4, fr = l & 15;
  const int m0 = blockIdx.x * 128;
  const int n0 = blockIdx.y * 128;

  __shared__ short sA[128 * 32];
  __shared__ short sB[128 * 32];
  f32x4 acc[4][4] = {};

  for (int k0 = 0; k0 < DM; k0 += 32) {
#pragma unroll
    for (int c = 0; c < 2; ++c) {
      int r = w * 32 + c * 16;
      gload_lds16(&A[(size_t)(m0 + r + (l >> 2)) * DM + k0 + (l & 3) * 8], &sA[r * 32]);
      gload_lds16(&W[(size_t)(n0 + r + (l >> 2)) * DM + k0 + (l & 3) * 8], &sB[r * 32]);
    }
    __syncthreads();
    short8 aF[4], bF[4];
#pragma unroll
    for (int m = 0; m < 4; ++m)
      aF[m] = *(const short8*)&sA[(wr * 64 + m * 16 + fr) * 32 + fq * 8];
#pragma unroll
    for (int n = 0; n < 4; ++n)
      bF[n] = *(const short8*)&sB[(wc * 64 + n * 16 + fr) * 32 + fq * 8];
#pragma unroll
    for (int m = 0; m < 4; ++m)
#pragma unroll
      for (int n = 0; n < 4; ++n)
        acc[m][n] = __builtin_amdgcn_mfma_f32_16x16x32_bf16(aF[m], bF[n], acc[m][n], 0, 0, 0);
    __syncthreads();
  }

#pragma unroll
  for (int m = 0; m < 4; ++m) {
    int row0 = m0 + wr * 64 + m * 16 + fq * 4;
#pragma unroll
    for (int n = 0; n < 4; ++n) {
      int col = n0 + wc * 64 + n * 16 + fr;
#pragma unroll
      for (int j = 0; j < 4; ++j)
        C[(size_t)(row0 + j) * DM + col] = acc[m][n][j];
    }
  }
}

// ---------------- flash attention v4: 4 blocks/CU, balanced big-first mapping ----------------
// Block = 128 q rows (4 waves x 32). Grid 1024 = 16 qt x 64 bh.
// Mapping: per-CU qt-sets sum to exactly 30 (68 K-tiles/CU); all 4 blocks of a
// CU share one bh (K/V L2-resident); big-qt blocks dispatch first.
__global__ __launch_bounds__(256, 4) void k_attn4(
    const short* __restrict__ Qb,   // [bh][t][dh]
    const short* __restrict__ Kb,   // [bh][t][dh]
    const short* __restrict__ Vtb,  // [bh][dh][t]
    short* __restrict__ Ob) {       // [b][t][h*64+d] bf16
  const int tid = threadIdx.x;
  const int w = tid >> 6, l = tid & 63;
  const int lq = l & 31, hi = l >> 5;
  const int id = blockIdx.x;
  const int g = id >> 3;
  const int r_ = g >> 3, a_ = r_ & 3, b_ = r_ >> 2;
  const int qt = 15 - (4 * b_ + ((a_ + b_) & 3));
  const int bh = (id & 7) + 8 * (g & 7);
  const int b = bh >> 4, h = bh & 15;
  const float K2 = 0.125f * 1.44269504f;  // 1/sqrt(64) * log2(e)

  __shared__ short lds[16384];  // sK dbuf [2][4096] | sVt dbuf [2][4096]; epi reuse
  short* sK = lds;
  short* sVt = lds + 8192;

  auto STAGE = [&](int buf, int kt) {
#pragma unroll
    for (int i = 0; i < 2; ++i) {
      int lin = i * 256 + tid;
      int row = lin >> 3, pseg = lin & 7;
      int gseg = pseg ^ (row & 7);
      gload_lds16(&Kb[((size_t)bh * T_ + kt * 64 + row) * DH + gseg * 8],
                  &sK[buf * 4096 + lin * 8]);
    }
#pragma unroll
    for (int i = 0; i < 2; ++i) {
      int lin = i * 256 + tid;
      int row = lin >> 3, pseg = lin & 7;
      int gseg = pseg ^ (row & 7);
      gload_lds16(&Vtb[((size_t)bh * DH + row) * T_ + kt * 64 + gseg * 8],
                  &sVt[buf * 4096 + lin * 8]);
    }
  };

  const int nkt = 2 * qt + 2;
  const int q0 = qt * 128 + w * 32;
  const int qg = q0 + lq;

  short8 qf[4];
#pragma unroll
  for (int c = 0; c < 4; ++c)
    qf[c] = *(const short8*)&Qb[((size_t)bh * T_ + qg) * DH + c * 16 + hi * 8];
  asm volatile("s_waitcnt vmcnt(0)" ::: "memory");

  float m = -3.0e38f, lsum = 0.f;
  f32x16 oacc[2] = {};

  auto COMPUTE = [&](int kt, int buf) {
    const int koff = buf * 4096, voff = buf * 4096;
    // ---- S^T = K · Q^T ----
    float s[32];
    __builtin_amdgcn_s_setprio(1);
#pragma unroll
    for (int st = 0; st < 2; ++st) {
      f32x16 acc = {};
#pragma unroll
      for (int c = 0; c < 4; ++c) {
        short8 kf = *(const short8*)&sK[koff + (st * 32 + lq) * 64 +
                                        (((2 * c + hi) ^ (lq & 7)) * 8)];
        acc = __builtin_amdgcn_mfma_f32_32x32x16_bf16(kf, qf[c], acc, 0, 0, 0);
      }
#pragma unroll
      for (int r = 0; r < 16; ++r) s[st * 16 + r] = acc[r];
    }
    __builtin_amdgcn_s_setprio(0);

    // ---- causal mask ----
    if (kt * 64 + 63 > q0) {
#pragma unroll
      for (int st = 0; st < 2; ++st)
#pragma unroll
        for (int r = 0; r < 16; ++r) {
          int kg = kt * 64 + st * 32 + (r & 3) + 8 * (r >> 2) + 4 * hi;
          if (kg > qg) s[st * 16 + r] = -1e30f;
        }
    }

    // ---- online softmax, defer-max (T13) ----
    float pm = s[0];
#pragma unroll
    for (int r = 1; r < 32; ++r) pm = fmaxf(pm, s[r]);
    pm = fmaxf(pm, __shfl_xor(pm, 32));
    if (__any(pm > m + 8.f)) {
      float nm = fmaxf(m, pm);
      float alpha = exp2f((m - nm) * K2);
      m = nm;
      lsum *= alpha;
#pragma unroll
      for (int dt = 0; dt < 2; ++dt)
#pragma unroll
        for (int r = 0; r < 16; ++r) oacc[dt][r] *= alpha;
    }
    float nmK = m * K2;
    float rs = 0.f;
#pragma unroll
    for (int r = 0; r < 32; ++r) {
      float p = exp2f(fmaf(s[r], K2, -nmK));
      s[r] = p;
      rs += p;
    }
    rs += __shfl_xor(rs, 32);
    lsum += rs;

    // ---- P -> bf16 B-fragments via cvt_pk + permlane32_swap (T12) ----
    short8 pb[4];
#pragma unroll
    for (int st = 0; st < 2; ++st) {
      unsigned x0 = cvtpk(s[st * 16 + 0], s[st * 16 + 1]);
      unsigned x1 = cvtpk(s[st * 16 + 2], s[st * 16 + 3]);
      unsigned y0 = cvtpk(s[st * 16 + 4], s[st * 16 + 5]);
      unsigned y1 = cvtpk(s[st * 16 + 6], s[st * 16 + 7]);
      uint2v r0 = __builtin_amdgcn_permlane32_swap(x0, y0, false, false);
      uint2v r1 = __builtin_amdgcn_permlane32_swap(x1, y1, false, false);
      unsigned x2 = cvtpk(s[st * 16 + 8], s[st * 16 + 9]);
      unsigned x3 = cvtpk(s[st * 16 + 10], s[st * 16 + 11]);
      unsigned y2 = cvtpk(s[st * 16 + 12], s[st * 16 + 13]);
      unsigned y3 = cvtpk(s[st * 16 + 14], s[st * 16 + 15]);
      uint2v r2 = __builtin_amdgcn_permlane32_swap(x2, y2, false, false);
      uint2v r3 = __builtin_amdgcn_permlane32_swap(x3, y3, false, false);
      uint4v ta, tb;
      ta[0] = r0[0]; ta[1] = r1[0]; ta[2] = r0[1]; ta[3] = r1[1];
      tb[0] = r2[0]; tb[1] = r3[0]; tb[2] = r2[1]; tb[3] = r3[1];
      pb[st * 2 + 0] = __builtin_bit_cast(short8, ta);
      pb[st * 2 + 1] = __builtin_bit_cast(short8, tb);
    }

    // ---- O^T += V^T · P ----
    __builtin_amdgcn_s_setprio(1);
#pragma unroll
    for (int dt = 0; dt < 2; ++dt) {
#pragma unroll
      for (int c = 0; c < 4; ++c) {
        short8 vf = *(const short8*)&sVt[voff + (dt * 32 + lq) * 64 +
                                         (((2 * c + hi) ^ (lq & 7)) * 8)];
        oacc[dt] = __builtin_amdgcn_mfma_f32_32x32x16_bf16(vf, pb[c], oacc[dt], 0, 0, 0);
      }
    }
    __builtin_amdgcn_s_setprio(0);
  };

  // ---- pipelined K/V loop: counted vmcnt, raw barriers (T3/T4) ----
  STAGE(0, 0);
  int cur = 0;
  for (int kt = 0; kt < nkt - 1; ++kt) {
    STAGE(cur ^ 1, kt + 1);
    asm volatile("s_waitcnt vmcnt(4)" ::: "memory");
    __builtin_amdgcn_s_barrier();
    __builtin_amdgcn_sched_barrier(0);
    COMPUTE(kt, cur);
    __builtin_amdgcn_s_barrier();
    cur ^= 1;
  }
  asm volatile("s_waitcnt vmcnt(0)" ::: "memory");
  __builtin_amdgcn_s_barrier();
  __builtin_amdgcn_sched_barrier(0);
  COMPUTE(nkt - 1, cur);

  // ---- epilogue: O^T -> LDS transpose -> coalesced bf16 stores ----
  __syncthreads();  // all waves done with staging buffers
  short* sO = lds + w * 2304;  // [32][72] padded
  float inv = 1.0f / lsum;
#pragma unroll
  for (int dt = 0; dt < 2; ++dt)
#pragma unroll
    for (int r = 0; r < 16; r += 2) {
      int dl = dt * 32 + (r & 3) + 8 * (r >> 2) + 4 * hi;
      unsigned pk2 = cvtpk(oacc[dt][r] * inv, oacc[dt][r + 1] * inv);
      *(unsigned*)&sO[lq * 72 + dl] = pk2;
    }
  __syncthreads();
  {
    int qr = l >> 1, hf = l & 1;
    const int tg = qt * 128 + w * 32 + qr;
#pragma unroll
    for (int ss = 0; ss < 4; ++ss) {
      short8 v = *(const short8*)&sO[qr * 72 + hf * 32 + ss * 8];
      *(short8*)&Ob[((size_t)(b * T_) + tg) * DM + h * 64 + hf * 32 + ss * 8] = v;
    }
  }
}

extern "C" void kernel_launch(void* const* d_in, const int* in_sizes, int n_in,
                              void* d_out, int out_size, void* d_ws, size_t ws_size,
                              hipStream_t stream) {
  const float* x     = (const float*)d_in[0];   // [4,2048,1024]
  const float* Wqkv  = (const float*)d_in[1];   // [3072,1024]
  const float* Wproj = (const float*)d_in[2];   // [1024,1024]
  float* out = (float*)d_out;

  short* ws = (short*)d_ws;
  short* xbf   = ws;                                  // 8192*1024
  short* wqkvb = xbf + (size_t)M_ * DM;               // 3072*1024
  short* wprjb = wqkvb + (size_t)3 * DM * DM;         // 1024*1024
  short* Qb    = wprjb + (size_t)DM * DM;             // 64*2048*64
  short* Kb    = Qb + (size_t)BH * T_ * DH;
  short* Vtb   = Kb + (size_t)BH * T_ * DH;           // transposed [bh][dh][t]
  short* Ob    = Vtb + (size_t)BH * T_ * DH;          // 8192*1024

  const int ncv = (M_ * DM + 3 * DM * DM + DM * DM) / 4;
  k_cvt3<<<(ncv + 255) / 256, 256, 0, stream>>>(
      (const float4*)x, (const float4*)Wqkv, (const float4*)Wproj,
      (ushort4*)xbf, (ushort4*)wqkvb, (ushort4*)wprjb);

  k_gemm_qkv<<<dim3(M_ / 128, 3 * DM / 128), 256, 0, stream>>>(xbf, wqkvb, Qb, Kb, Vtb);
  k_attn4<<<1024, 256, 0, stream>>>(Qb, Kb, Vtb, Ob);
  k_gemm_proj<<<dim3(M_ / 128, DM / 128), 256, 0, stream>>>(Ob, wprjb, out);
}

// Round 5
// 155.664 us; speedup vs baseline: 1.4384x; 1.1786x over previous
//
#include <hip/hip_runtime.h>
#include <hip/hip_bf16.h>
#include <math.h>

typedef __attribute__((ext_vector_type(8))) short short8;
typedef __attribute__((ext_vector_type(4))) float f32x4;
typedef __attribute__((ext_vector_type(16))) float f32x16;
typedef __attribute__((ext_vector_type(2))) unsigned uint2v;
typedef __attribute__((ext_vector_type(4))) unsigned uint4v;

#define B_  4
#define T_  2048
#define DM  1024
#define NH  16
#define DH  64
#define BH  (B_*NH)   // 64
#define M_  (B_*T_)   // 8192

static __device__ __forceinline__ short f2bf(float f) {
  unsigned u = __float_as_uint(f);
  unsigned r = (u + 0x7fff + ((u >> 16) & 1)) >> 16;
  return (short)r;
}

static __device__ __forceinline__ unsigned cvtpk(float lo, float hi) {
  unsigned r;
  asm("v_cvt_pk_bf16_f32 %0, %1, %2" : "=v"(r) : "v"(lo), "v"(hi));
  return r;
}

static __device__ __forceinline__ void gload_lds16(const void* g, void* l) {
  __builtin_amdgcn_global_load_lds((const __attribute__((address_space(1))) void*)g,
                                   (__attribute__((address_space(3))) void*)l, 16, 0, 0);
}

// ---------------- fp32 -> bf16 convert, all three tensors in one launch ----------------
__global__ void k_cvt3(const float4* __restrict__ x, const float4* __restrict__ wq,
                       const float4* __restrict__ wp, ushort4* __restrict__ ox,
                       ushort4* __restrict__ oq, ushort4* __restrict__ op) {
  const int n1 = M_ * DM / 4, n2 = 3 * DM * DM / 4, n3 = DM * DM / 4;
  int i = blockIdx.x * 256 + threadIdx.x;
  const float4* src;
  ushort4* dst;
  int j = i;
  if (i < n1) { src = x; dst = ox; }
  else if (i < n1 + n2) { src = wq; dst = oq; j = i - n1; }
  else if (i < n1 + n2 + n3) { src = wp; dst = op; j = i - n1 - n2; }
  else return;
  float4 v = src[j];
  ushort4 o;
  o.x = (ushort)f2bf(v.x); o.y = (ushort)f2bf(v.y);
  o.z = (ushort)f2bf(v.z); o.w = (ushort)f2bf(v.w);
  dst[j] = o;
}

// ================= GEMM core macros (128x128 tile, BK=64, dbuf, swizzled) =================
// Staging: thread chunk lin -> row=lin>>3, pseg=lin&7; global seg = pseg^(row&7)
// (linear LDS dest for global_load_lds; swizzle realized on the global address).
// Frag read: row r, seg s -> lds[r*64 + ((s^(r&7))*8)]  (conflict-free b128).

#define GEMM_STAGE(SRCA, SRCB, dA, dB, m0_, n0_, k0_)                          \
  {                                                                            \
    _Pragma("unroll")                                                          \
    for (int i = 0; i < 4; ++i) {                                              \
      int lin = i * 256 + tid;                                                 \
      int row = lin >> 3, pseg = lin & 7;                                      \
      int gseg = pseg ^ (row & 7);                                             \
      gload_lds16(&SRCA[(size_t)((m0_) + row) * DM + (k0_) + gseg * 8],        \
                  &(dA)[lin * 8]);                                             \
    }                                                                          \
    _Pragma("unroll")                                                          \
    for (int i = 0; i < 4; ++i) {                                              \
      int lin = i * 256 + tid;                                                 \
      int row = lin >> 3, pseg = lin & 7;                                      \
      int gseg = pseg ^ (row & 7);                                             \
      gload_lds16(&SRCB[(size_t)((n0_) + row) * DM + (k0_) + gseg * 8],        \
                  &(dB)[lin * 8]);                                             \
    }                                                                          \
  }

#define GEMM_COMPUTE(pA, pB)                                                   \
  {                                                                            \
    _Pragma("unroll")                                                          \
    for (int kk = 0; kk < 2; ++kk) {                                           \
      short8 aF[4], bF[4];                                                     \
      _Pragma("unroll")                                                        \
      for (int m = 0; m < 4; ++m)                                              \
        aF[m] = *(const short8*)&(pA)[(wr * 64 + m * 16 + fr) * 64 +           \
                                      (((kk * 4 + fq) ^ (fr & 7)) * 8)];       \
      _Pragma("unroll")                                                        \
      for (int n = 0; n < 4; ++n)                                              \
        bF[n] = *(const short8*)&(pB)[(wc * 64 + n * 16 + fr) * 64 +           \
                                      (((kk * 4 + fq) ^ (fr & 7)) * 8)];       \
      __builtin_amdgcn_s_setprio(1);                                           \
      _Pragma("unroll")                                                        \
      for (int m = 0; m < 4; ++m)                                              \
        _Pragma("unroll")                                                      \
        for (int n = 0; n < 4; ++n)                                            \
          acc[m][n] = __builtin_amdgcn_mfma_f32_16x16x32_bf16(aF[m], bF[n],    \
                                                              acc[m][n], 0, 0, 0); \
      __builtin_amdgcn_s_setprio(0);                                           \
    }                                                                          \
  }

#define GEMM_KLOOP(SRCA, SRCB, m0_, n0_)                                       \
  GEMM_STAGE(SRCA, SRCB, sA0, sB0, m0_, n0_, 0);                               \
  {                                                                            \
    _Pragma("unroll 1")                                                        \
    for (int t = 0; t < 16; ++t) {                                             \
      short* pA = (t & 1) ? sA1 : sA0;                                         \
      short* pB = (t & 1) ? sB1 : sB0;                                         \
      if (t < 15) {                                                            \
        short* nA = (t & 1) ? sA0 : sA1;                                       \
        short* nB = (t & 1) ? sB0 : sB1;                                       \
        GEMM_STAGE(SRCA, SRCB, nA, nB, m0_, n0_, (t + 1) * 64);                \
        asm volatile("s_waitcnt vmcnt(8)" ::: "memory");                       \
      } else {                                                                 \
        asm volatile("s_waitcnt vmcnt(0)" ::: "memory");                       \
      }                                                                        \
      __builtin_amdgcn_s_barrier();                                            \
      __builtin_amdgcn_sched_barrier(0);                                       \
      GEMM_COMPUTE(pA, pB);                                                    \
      asm volatile("" ::: "memory");                                           \
      __builtin_amdgcn_s_barrier();                                            \
    }                                                                          \
  }

// ---------------- QKV GEMM ----------------
// grid (64, 24). Q,K -> [bh][t][dh]; V -> transposed [bh][dh][t].
// Epilogue goes through LDS (reusing staging buffers) for coalesced short8 stores.
__global__ __launch_bounds__(256, 2) void k_gemm_qkv(
    const short* __restrict__ A,    // [M_, DM]
    const short* __restrict__ W,    // [3*DM, DM]
    short* __restrict__ Qb, short* __restrict__ Kb, short* __restrict__ Vtb) {
  const int tid = threadIdx.x;
  const int w = tid >> 6, l = tid & 63;
  const int wr = w >> 1, wc = w & 1;
  const int fq = l >> 4, fr = l & 15;
  const int m0 = blockIdx.x * 128;
  const int n0 = blockIdx.y * 128;

  __shared__ short lds[32768];       // 64 KB: staging dbuf; reused by epilogue
  short* sA0 = lds;
  short* sA1 = lds + 8192;
  short* sB0 = lds + 16384;
  short* sB1 = lds + 24576;

  f32x4 acc[4][4] = {};
  GEMM_KLOOP(A, W, m0, n0);
  __syncthreads();   // staging done; reuse LDS for epilogue

  // ---- epilogue via LDS: [128][136] padded (byte stride 272, 16B-aligned rows) ----
  short* sE = lds;
  const int part = n0 >> 10;          // 0=Q 1=K 2=V
  const int b = m0 >> 11, tloc = m0 & 2047;

  if (part < 2) {
    // LDS[row=t_local][col]: scalar bf16 writes (one-time), coalesced readout
#pragma unroll
    for (int m = 0; m < 4; ++m)
#pragma unroll
      for (int n = 0; n < 4; ++n)
#pragma unroll
        for (int j = 0; j < 4; ++j)
          sE[(wr * 64 + m * 16 + fq * 4 + j) * 136 + wc * 64 + n * 16 + fr] =
              f2bf(acc[m][n][j]);
    __syncthreads();
    short* dst = part ? Kb : Qb;
    const int h0 = (n0 & 1023) >> 6;
#pragma unroll
    for (int v = 0; v < 8; ++v) {
      int vid = v * 256 + tid;
      int row = vid >> 4, seg = vid & 15;    // 16 segs of 8 shorts = 128 cols
      short8 val = *(const short8*)&sE[row * 136 + seg * 8];
      int h = h0 + (seg >> 3), dh0 = (seg & 7) * 8;
      *(short8*)&dst[(((size_t)(b * NH + h) * T_ + tloc + row)) * DH + dh0] = val;
    }
  } else {
    // V: LDS pre-transposed [col][t_local]; 4 consecutive-t accs pack to one b64 write
#pragma unroll
    for (int m = 0; m < 4; ++m)
#pragma unroll
      for (int n = 0; n < 4; ++n) {
        uint2v pk;
        pk[0] = cvtpk(acc[m][n][0], acc[m][n][1]);
        pk[1] = cvtpk(acc[m][n][2], acc[m][n][3]);
        *(uint2v*)&sE[(wc * 64 + n * 16 + fr) * 136 + wr * 64 + m * 16 + fq * 4] = pk;
      }
    __syncthreads();
    const int h0 = (n0 & 1023) >> 6;
#pragma unroll
    for (int v = 0; v < 8; ++v) {
      int vid = v * 256 + tid;
      int col = vid >> 4, seg = vid & 15;    // col 0..127, seg: 8-t chunk
      short8 val = *(const short8*)&sE[col * 136 + seg * 8];
      int h = h0 + (col >> 6), dh = col & 63;
      *(short8*)&Vtb[(((size_t)(b * NH + h) * DH + dh)) * T_ + tloc + seg * 8] = val;
    }
  }
}

// ---------------- proj GEMM: out[m][n] = sum_k O[m][k]*Wp[n][k] (fp32 out) ----------------
__global__ __launch_bounds__(256, 2) void k_gemm_proj(
    const short* __restrict__ A,    // [M_, DM] bf16 (attention out)
    const short* __restrict__ W,    // [DM, DM] bf16
    float* __restrict__ C) {
  const int tid = threadIdx.x;
  const int w = tid >> 6, l = tid & 63;
  const int wr = w >> 1, wc = w & 1;
  const int fq = l >> 4, fr = l & 15;
  const int m0 = blockIdx.x * 128;
  const int n0 = blockIdx.y * 128;

  __shared__ short lds[32768];
  short* sA0 = lds;
  short* sA1 = lds + 8192;
  short* sB0 = lds + 16384;
  short* sB1 = lds + 24576;

  f32x4 acc[4][4] = {};
  GEMM_KLOOP(A, W, m0, n0);

  // fp32 stores: lanes fr -> consecutive cols, already coalesced
#pragma unroll
  for (int m = 0; m < 4; ++m) {
    int row0 = m0 + wr * 64 + m * 16 + fq * 4;
#pragma unroll
    for (int n = 0; n < 4; ++n) {
      int col = n0 + wc * 64 + n * 16 + fr;
#pragma unroll
      for (int j = 0; j < 4; ++j)
        C[(size_t)(row0 + j) * DM + col] = acc[m][n][j];
    }
  }
}

// ---------------- flash attention v4 (unchanged from round 4) ----------------
__global__ __launch_bounds__(256, 4) void k_attn4(
    const short* __restrict__ Qb,   // [bh][t][dh]
    const short* __restrict__ Kb,   // [bh][t][dh]
    const short* __restrict__ Vtb,  // [bh][dh][t]
    short* __restrict__ Ob) {       // [b][t][h*64+d] bf16
  const int tid = threadIdx.x;
  const int w = tid >> 6, l = tid & 63;
  const int lq = l & 31, hi = l >> 5;
  const int id = blockIdx.x;
  const int g = id >> 3;
  const int r_ = g >> 3, a_ = r_ & 3, b_ = r_ >> 2;
  const int qt = 15 - (4 * b_ + ((a_ + b_) & 3));
  const int bh = (id & 7) + 8 * (g & 7);
  const int b = bh >> 4, h = bh & 15;
  const float K2 = 0.125f * 1.44269504f;  // 1/sqrt(64) * log2(e)

  __shared__ short lds[16384];  // sK dbuf [2][4096] | sVt dbuf [2][4096]; epi reuse
  short* sK = lds;
  short* sVt = lds + 8192;

  auto STAGE = [&](int buf, int kt) {
#pragma unroll
    for (int i = 0; i < 2; ++i) {
      int lin = i * 256 + tid;
      int row = lin >> 3, pseg = lin & 7;
      int gseg = pseg ^ (row & 7);
      gload_lds16(&Kb[((size_t)bh * T_ + kt * 64 + row) * DH + gseg * 8],
                  &sK[buf * 4096 + lin * 8]);
    }
#pragma unroll
    for (int i = 0; i < 2; ++i) {
      int lin = i * 256 + tid;
      int row = lin >> 3, pseg = lin & 7;
      int gseg = pseg ^ (row & 7);
      gload_lds16(&Vtb[((size_t)bh * DH + row) * T_ + kt * 64 + gseg * 8],
                  &sVt[buf * 4096 + lin * 8]);
    }
  };

  const int nkt = 2 * qt + 2;
  const int q0 = qt * 128 + w * 32;
  const int qg = q0 + lq;

  short8 qf[4];
#pragma unroll
  for (int c = 0; c < 4; ++c)
    qf[c] = *(const short8*)&Qb[((size_t)bh * T_ + qg) * DH + c * 16 + hi * 8];
  asm volatile("s_waitcnt vmcnt(0)" ::: "memory");

  float m = -3.0e38f, lsum = 0.f;
  f32x16 oacc[2] = {};

  auto COMPUTE = [&](int kt, int buf) {
    const int koff = buf * 4096, voff = buf * 4096;
    // ---- S^T = K · Q^T ----
    float s[32];
    __builtin_amdgcn_s_setprio(1);
#pragma unroll
    for (int st = 0; st < 2; ++st) {
      f32x16 acc = {};
#pragma unroll
      for (int c = 0; c < 4; ++c) {
        short8 kf = *(const short8*)&sK[koff + (st * 32 + lq) * 64 +
                                        (((2 * c + hi) ^ (lq & 7)) * 8)];
        acc = __builtin_amdgcn_mfma_f32_32x32x16_bf16(kf, qf[c], acc, 0, 0, 0);
      }
#pragma unroll
      for (int r = 0; r < 16; ++r) s[st * 16 + r] = acc[r];
    }
    __builtin_amdgcn_s_setprio(0);

    // ---- causal mask ----
    if (kt * 64 + 63 > q0) {
#pragma unroll
      for (int st = 0; st < 2; ++st)
#pragma unroll
        for (int r = 0; r < 16; ++r) {
          int kg = kt * 64 + st * 32 + (r & 3) + 8 * (r >> 2) + 4 * hi;
          if (kg > qg) s[st * 16 + r] = -1e30f;
        }
    }

    // ---- online softmax, defer-max (T13) ----
    float pm = s[0];
#pragma unroll
    for (int r = 1; r < 32; ++r) pm = fmaxf(pm, s[r]);
    pm = fmaxf(pm, __shfl_xor(pm, 32));
    if (__any(pm > m + 8.f)) {
      float nm = fmaxf(m, pm);
      float alpha = exp2f((m - nm) * K2);
      m = nm;
      lsum *= alpha;
#pragma unroll
      for (int dt = 0; dt < 2; ++dt)
#pragma unroll
        for (int r = 0; r < 16; ++r) oacc[dt][r] *= alpha;
    }
    float nmK = m * K2;
    float rs = 0.f;
#pragma unroll
    for (int r = 0; r < 32; ++r) {
      float p = exp2f(fmaf(s[r], K2, -nmK));
      s[r] = p;
      rs += p;
    }
    rs += __shfl_xor(rs, 32);
    lsum += rs;

    // ---- P -> bf16 B-fragments via cvt_pk + permlane32_swap (T12) ----
    short8 pb[4];
#pragma unroll
    for (int st = 0; st < 2; ++st) {
      unsigned x0 = cvtpk(s[st * 16 + 0], s[st * 16 + 1]);
      unsigned x1 = cvtpk(s[st * 16 + 2], s[st * 16 + 3]);
      unsigned y0 = cvtpk(s[st * 16 + 4], s[st * 16 + 5]);
      unsigned y1 = cvtpk(s[st * 16 + 6], s[st * 16 + 7]);
      uint2v r0 = __builtin_amdgcn_permlane32_swap(x0, y0, false, false);
      uint2v r1 = __builtin_amdgcn_permlane32_swap(x1, y1, false, false);
      unsigned x2 = cvtpk(s[st * 16 + 8], s[st * 16 + 9]);
      unsigned x3 = cvtpk(s[st * 16 + 10], s[st * 16 + 11]);
      unsigned y2 = cvtpk(s[st * 16 + 12], s[st * 16 + 13]);
      unsigned y3 = cvtpk(s[st * 16 + 14], s[st * 16 + 15]);
      uint2v r2 = __builtin_amdgcn_permlane32_swap(x2, y2, false, false);
      uint2v r3 = __builtin_amdgcn_permlane32_swap(x3, y3, false, false);
      uint4v ta, tb;
      ta[0] = r0[0]; ta[1] = r1[0]; ta[2] = r0[1]; ta[3] = r1[1];
      tb[0] = r2[0]; tb[1] = r3[0]; tb[2] = r2[1]; tb[3] = r3[1];
      pb[st * 2 + 0] = __builtin_bit_cast(short8, ta);
      pb[st * 2 + 1] = __builtin_bit_cast(short8, tb);
    }

    // ---- O^T += V^T · P ----
    __builtin_amdgcn_s_setprio(1);
#pragma unroll
    for (int dt = 0; dt < 2; ++dt) {
#pragma unroll
      for (int c = 0; c < 4; ++c) {
        short8 vf = *(const short8*)&sVt[voff + (dt * 32 + lq) * 64 +
                                         (((2 * c + hi) ^ (lq & 7)) * 8)];
        oacc[dt] = __builtin_amdgcn_mfma_f32_32x32x16_bf16(vf, pb[c], oacc[dt], 0, 0, 0);
      }
    }
    __builtin_amdgcn_s_setprio(0);
  };

  // ---- pipelined K/V loop: counted vmcnt, raw barriers (T3/T4) ----
  STAGE(0, 0);
  int cur = 0;
  for (int kt = 0; kt < nkt - 1; ++kt) {
    STAGE(cur ^ 1, kt + 1);
    asm volatile("s_waitcnt vmcnt(4)" ::: "memory");
    __builtin_amdgcn_s_barrier();
    __builtin_amdgcn_sched_barrier(0);
    COMPUTE(kt, cur);
    __builtin_amdgcn_s_barrier();
    cur ^= 1;
  }
  asm volatile("s_waitcnt vmcnt(0)" ::: "memory");
  __builtin_amdgcn_s_barrier();
  __builtin_amdgcn_sched_barrier(0);
  COMPUTE(nkt - 1, cur);

  // ---- epilogue: O^T -> LDS transpose -> coalesced bf16 stores ----
  __syncthreads();  // all waves done with staging buffers
  short* sO = lds + w * 2304;  // [32][72] padded
  float inv = 1.0f / lsum;
#pragma unroll
  for (int dt = 0; dt < 2; ++dt)
#pragma unroll
    for (int r = 0; r < 16; r += 2) {
      int dl = dt * 32 + (r & 3) + 8 * (r >> 2) + 4 * hi;
      unsigned pk2 = cvtpk(oacc[dt][r] * inv, oacc[dt][r + 1] * inv);
      *(unsigned*)&sO[lq * 72 + dl] = pk2;
    }
  __syncthreads();
  {
    int qr = l >> 1, hf = l & 1;
    const int tg = qt * 128 + w * 32 + qr;
#pragma unroll
    for (int ss = 0; ss < 4; ++ss) {
      short8 v = *(const short8*)&sO[qr * 72 + hf * 32 + ss * 8];
      *(short8*)&Ob[((size_t)(b * T_) + tg) * DM + h * 64 + hf * 32 + ss * 8] = v;
    }
  }
}

extern "C" void kernel_launch(void* const* d_in, const int* in_sizes, int n_in,
                              void* d_out, int out_size, void* d_ws, size_t ws_size,
                              hipStream_t stream) {
  const float* x     = (const float*)d_in[0];   // [4,2048,1024]
  const float* Wqkv  = (const float*)d_in[1];   // [3072,1024]
  const float* Wproj = (const float*)d_in[2];   // [1024,1024]
  float* out = (float*)d_out;

  short* ws = (short*)d_ws;
  short* xbf   = ws;                                  // 8192*1024
  short* wqkvb = xbf + (size_t)M_ * DM;               // 3072*1024
  short* wprjb = wqkvb + (size_t)3 * DM * DM;         // 1024*1024
  short* Qb    = wprjb + (size_t)DM * DM;             // 64*2048*64
  short* Kb    = Qb + (size_t)BH * T_ * DH;
  short* Vtb   = Kb + (size_t)BH * T_ * DH;           // transposed [bh][dh][t]
  short* Ob    = Vtb + (size_t)BH * T_ * DH;          // 8192*1024

  const int ncv = (M_ * DM + 3 * DM * DM + DM * DM) / 4;
  k_cvt3<<<(ncv + 255) / 256, 256, 0, stream>>>(
      (const float4*)x, (const float4*)Wqkv, (const float4*)Wproj,
      (ushort4*)xbf, (ushort4*)wqkvb, (ushort4*)wprjb);

  k_gemm_qkv<<<dim3(M_ / 128, 3 * DM / 128), 256, 0, stream>>>(xbf, wqkvb, Qb, Kb, Vtb);
  k_attn4<<<1024, 256, 0, stream>>>(Qb, Kb, Vtb, Ob);
  k_gemm_proj<<<dim3(M_ / 128, DM / 128), 256, 0, stream>>>(Ob, wprjb, out);
}